// Round 8
// baseline (1304.005 us; speedup 1.0000x reference)
//
#include <hip/hip_runtime.h>
#include <hip/hip_fp16.h>
#include <math.h>

#define WW 128
#define HH 128
#define DD 128
#define HW (WW * HH)
#define VOL (WW * HH * DD)

typedef _Float16 f16x8 __attribute__((ext_vector_type(8)));
typedef _Float16 f16x4 __attribute__((ext_vector_type(4)));
typedef _Float16 f16x2 __attribute__((ext_vector_type(2)));
typedef float f32x4 __attribute__((ext_vector_type(4)));
typedef int int4v __attribute__((ext_vector_type(4)));

__device__ __forceinline__ float ldv(const float* p) { return *p; }
__device__ __forceinline__ float ldv(const _Float16* p) { return (float)*p; }
__device__ __forceinline__ void stv(float* p, float v) { *p = v; }
__device__ __forceinline__ void stv(_Float16* p, float v) { *p = (_Float16)v; }

// ==========================================================================
// cvt_x: planar fp32 (8ch) -> channel-interleaved f16x8 [d][h][w][c8]
// ==========================================================================
__global__ __launch_bounds__(256) void cvt_x(const float* __restrict__ x,
                                             _Float16* __restrict__ xi)
{
    const size_t v = (size_t)blockIdx.x * 256 + threadIdx.x;
    f16x8 o;
#pragma unroll
    for (int c = 0; c < 8; ++c) o[c] = (_Float16)x[(size_t)c * VOL + v];
    *(f16x8*)(xi + v * 8) = o;
}

// ==========================================================================
// Implicit-GEMM 3x3x3 conv via MFMA f16, input channel-interleaved f16x8.
//   D[OC, vox] = W[OC, K=216] * im2col[K, vox], K order k = tap*8 + c.
// R8: tile 2d x 4h x 64w -> halo 4x6x66 sites = 25,344 B LDS
//     => 6 blocks/CU resident (was 4 at 38.4 KB), 24 waves/CU.
//     2 waves per d-slice, each owns 8 n-tiles of 16 voxels.
// OM: 0 = interleaved 8-ch out, 1 = [vox][32] L1-normed weight field
//     (bpermute transpose -> one dwordx4 store per lane), 2 = planar 1-ch.
// ==========================================================================
template <int OC, bool RELU, int OM, typename TO>
__global__ __launch_bounds__(256) void conv_mfma(const _Float16* __restrict__ in,
                                                 const float* __restrict__ wt,
                                                 const float* __restrict__ bias,
                                                 TO* __restrict__ out)
{
    __shared__ f16x8 hal[4 * 6 * 66];

    const int bid  = blockIdx.x;           // 4096 blocks: 64d x 32h x 2w
    const int wblk = bid & 1;
    const int hblk = (bid >> 1) & 31;
    const int dblk = bid >> 6;
    const int d0 = dblk * 2, h0 = hblk * 4, w0 = wblk * 64;

    const int tid = threadIdx.x;
    for (int s = tid; s < 4 * 6 * 66; s += 256) {
        const int dd = s / (6 * 66);
        const int r  = s % (6 * 66);
        const int hh = r / 66;
        const int ww = r % 66;
        const int gd = d0 + dd - 1, gh = h0 + hh - 1, gw = w0 + ww - 1;
        f16x8 v = {};
        if ((unsigned)gd < (unsigned)DD && (unsigned)gh < (unsigned)HH &&
            (unsigned)gw < (unsigned)WW)
            v = *(const f16x8*)(in + ((size_t)gd * HW + (size_t)gh * WW + gw) * 8);
        hal[s] = v;
    }

    const int lane = tid & 63;
    const int wid  = tid >> 6;
    const int dloc = wid >> 1;             // local d slice 0..1
    const int ntb  = (wid & 1) * 8;        // this wave's n-tile base
    const int n    = lane & 15;
    const int quad = lane >> 4;

    constexpr int MT = (OC > 16) ? 2 : 1;
    f16x8 afr[MT][7];
#pragma unroll
    for (int s = 0; s < 7; ++s) {
        const int tap = s * 4 + quad;      // k = tap*8 + c
#pragma unroll
        for (int mt = 0; mt < MT; ++mt) {
            const int m = mt * 16 + n;
            f16x8 a = {};
            if (tap < 27 && m < OC) {
#pragma unroll
                for (int j = 0; j < 8; ++j)
                    a[j] = (_Float16)wt[(size_t)m * 216 + (size_t)j * 27 + tap];
            }
            afr[mt][s] = a;
        }
    }

    int boff[7];
#pragma unroll
    for (int s = 0; s < 7; ++s) {
        int tap = s * 4 + quad;
        if (tap > 26) tap = 26;            // A is zero there
        const int kd = tap / 9, kh = (tap % 9) / 3, kw = tap % 3;
        boff[s] = (dloc + kd) * (6 * 66) + kh * 66 + kw + n;
    }

    float bv[MT][4];
#pragma unroll
    for (int mt = 0; mt < MT; ++mt)
#pragma unroll
        for (int r = 0; r < 4; ++r) {
            const int o = mt * 16 + quad * 4 + r;
            bv[mt][r] = ((OM != 1) && bias != nullptr && o < OC) ? bias[o] : 0.f;
        }

    __syncthreads();

    const size_t outbase = (size_t)(d0 + dloc) * HW + (size_t)h0 * WW + w0;

#pragma unroll 1
    for (int it = 0; it < 8; ++it) {
        const int nt = ntb + it;
        const int hl = nt >> 2, wseg = nt & 3;
        const int add = hl * 66 + wseg * 16;
        f32x4 acc[MT];
#pragma unroll
        for (int mt = 0; mt < MT; ++mt) {
            acc[mt][0] = bv[mt][0]; acc[mt][1] = bv[mt][1];
            acc[mt][2] = bv[mt][2]; acc[mt][3] = bv[mt][3];
        }
#pragma unroll
        for (int s = 0; s < 7; ++s) {
            const f16x8 b = hal[boff[s] + add];
            acc[0] = __builtin_amdgcn_mfma_f32_16x16x32_f16(afr[0][s], b, acc[0], 0, 0, 0);
            if (MT > 1)
                acc[1] = __builtin_amdgcn_mfma_f32_16x16x32_f16(afr[1][s], b, acc[1], 0, 0, 0);
        }
        const size_t vox = outbase + (size_t)hl * WW + wseg * 16 + n;

        if (OM == 0) {
            if (quad < 2) {
                f16x4 o4;
#pragma unroll
                for (int r = 0; r < 4; ++r) {
                    float v = acc[0][r];
                    if (RELU) v = fmaxf(v, 0.f);
                    o4[r] = (_Float16)v;
                }
                *(f16x4*)((_Float16*)out + vox * 8 + quad * 4) = o4;
            }
        } else if (OM == 1) {
            // ---- L1 norm: tree-reduce in-lane, then 2 shfls across the group
            float t0 = fabsf(acc[0][0]) + fabsf(acc[0][1]);
            float t1 = fabsf(acc[0][2]) + fabsf(acc[0][3]);
            float ssum;
            if (MT > 1) {
                float t2 = fabsf(acc[1][0]) + fabsf(acc[1][1]);
                float t3 = fabsf(acc[1][2]) + fabsf(acc[1][3]);
                ssum = (t0 + t1) + (t2 + t3);
            } else {
                ssum = t0 + t1;
            }
            ssum += __shfl_xor(ssum, 16);
            ssum += __shfl_xor(ssum, 32);
            const float inv = 1.0f / fmaxf(ssum, 1e-12f);
            int p[2][2];
#pragma unroll
            for (int mt = 0; mt < MT; ++mt)
#pragma unroll
                for (int rr = 0; rr < 2; ++rr) {
                    f16x2 t;
                    t[0] = (_Float16)(acc[mt][2 * rr] * inv);
                    t[1] = (_Float16)(acc[mt][2 * rr + 1] * inv);
                    p[mt][rr] = __builtin_bit_cast(int, t);
                }
            int4v wv;
#pragma unroll
            for (int w = 0; w < 4; ++w) {
                const int sq = (2 * quad + (w >> 1)) & 3;
                const int bidx = ((sq << 4) | n) << 2;
                const int a0 = __builtin_amdgcn_ds_bpermute(bidx, p[0][w & 1]);
                const int a1 = __builtin_amdgcn_ds_bpermute(bidx, p[1][w & 1]);
                wv[w] = (quad < 2) ? a0 : a1;
            }
            *(int4v*)((_Float16*)out + (vox << 5) + (quad << 3)) = wv;
        } else { // OM == 2, OC = 1 planar
            if (quad == 0) {
                float v = acc[0][0];
                if (RELU) v = fmaxf(v, 0.f);
                stv((TO*)out + vox, v);
            }
        }
    }
}

// ==========================================================================
// adapt8 (R6 form — 1 voxel/thread, fully coalesced): per-voxel 27-tap
// weights [vox][32] fp16, 8 interleaved channels. 4 f16x8 weight loads +
// 27 f16x8 neighbor loads, fp32 accumulate via v_fma_mix.
// ==========================================================================
__global__ __launch_bounds__(256) void adapt8(const _Float16* __restrict__ in,
                                              const _Float16* __restrict__ wn,
                                              _Float16* __restrict__ out)
{
    const int tid = threadIdx.x;
    const int bid = blockIdx.x;            // 8192 = 128 d x 64 h-pairs
    const int d = bid >> 6;
    const int h = ((bid & 63) << 1) + (tid >> 7);
    const int w = tid & 127;
    const size_t vox = (size_t)d * HW + (size_t)h * WW + w;

    const f16x8* wrow = (const f16x8*)(wn + (vox << 5));
    f16x8 wkv[4];
#pragma unroll
    for (int j = 0; j < 4; ++j) wkv[j] = wrow[j];

    float acc[8] = {0.f, 0.f, 0.f, 0.f, 0.f, 0.f, 0.f, 0.f};
#pragma unroll
    for (int kd = 0; kd < 3; ++kd) {
        const int gd = d + kd - 1;
#pragma unroll
        for (int kh = 0; kh < 3; ++kh) {
            const int gh = h + kh - 1;
#pragma unroll
            for (int kw = 0; kw < 3; ++kw) {
                const int gw = w + kw - 1;
                const bool ok = ((unsigned)gd < (unsigned)DD) &&
                                ((unsigned)gh < (unsigned)HH) &&
                                ((unsigned)gw < (unsigned)WW);
                f16x8 xv = {};
                if (ok)
                    xv = *(const f16x8*)(in + ((size_t)gd * HW + (size_t)gh * WW + gw) * 8);
                const int t = kd * 9 + kh * 3 + kw;
                const float wvv = (float)wkv[t >> 3][t & 7];
#pragma unroll
                for (int c = 0; c < 8; ++c) acc[c] += wvv * (float)xv[c];
            }
        }
    }
    f16x8 o;
#pragma unroll
    for (int c = 0; c < 8; ++c) o[c] = (_Float16)acc[c];
    *(f16x8*)(out + vox * 8) = o;
}

// ==========================================================================
// adapt1: 1 channel, planar in/out; weights [vox][32]. Thread = 1 voxel.
// ==========================================================================
template <typename TOUT>
__global__ __launch_bounds__(256) void adapt1(const _Float16* __restrict__ in,
                                              const _Float16* __restrict__ wn,
                                              TOUT* __restrict__ out)
{
    const size_t vox = (size_t)blockIdx.x * 256 + threadIdx.x;
    const int w = (int)(vox & 127);
    const int h = (int)((vox >> 7) & 127);
    const int d = (int)(vox >> 14);

    const f16x8* wrow = (const f16x8*)(wn + (vox << 5));
    f16x8 wkv[4];
#pragma unroll
    for (int j = 0; j < 4; ++j) wkv[j] = wrow[j];

    float acc = 0.f;
#pragma unroll
    for (int kd = 0; kd < 3; ++kd) {
        const int gd = d + kd - 1;
#pragma unroll
        for (int kh = 0; kh < 3; ++kh) {
            const int gh = h + kh - 1;
#pragma unroll
            for (int kw = 0; kw < 3; ++kw) {
                const int gw = w + kw - 1;
                const bool ok = ((unsigned)gd < (unsigned)DD) &&
                                ((unsigned)gh < (unsigned)HH) &&
                                ((unsigned)gw < (unsigned)WW);
                float xv = 0.f;
                if (ok)
                    xv = (float)in[(size_t)gd * HW + (size_t)gh * WW + gw];
                const int t = kd * 9 + kh * 3 + kw;
                acc += (float)wkv[t >> 3][t & 7] * xv;
            }
        }
    }
    stv(out + vox, acc);
}

extern "C" void kernel_launch(void* const* d_in, const int* in_sizes, int n_in,
                              void* d_out, int out_size, void* d_ws, size_t ws_size,
                              hipStream_t stream)
{
    (void)in_sizes; (void)n_in; (void)out_size; (void)ws_size;

    const float* x      = (const float*)d_in[0];
    const float* ac1_w1 = (const float*)d_in[1];
    const float* ac1_b1 = (const float*)d_in[2];
    const float* ac1_w2 = (const float*)d_in[3];
    const float* ac2_w1 = (const float*)d_in[4];
    const float* ac2_b1 = (const float*)d_in[5];
    const float* ac2_w2 = (const float*)d_in[6];
    const float* ac3_w1 = (const float*)d_in[7];
    const float* ac3_b1 = (const float*)d_in[8];
    const float* ac3_w2 = (const float*)d_in[9];
    const float* mid_w  = (const float*)d_in[10];
    const float* mid_b  = (const float*)d_in[11];
    const float* out_w  = (const float*)d_in[12];
    const float* out_b  = (const float*)d_in[13];
    float* outp = (float*)d_out;

    // fp16 scratch, 192 MB total:
    // Wb = [vox][32] weight field (32V) | B1i = 8V interleaved | B2i = 8V interleaved
    const size_t V = (size_t)VOL;
    _Float16* Wb  = (_Float16*)d_ws;
    _Float16* B1i = Wb + 32 * V;
    _Float16* B2i = B1i + 8 * V;
    _Float16* F0  = B2i;        // block-3 planar 1-ch ping-pong (B2i free there)
    _Float16* F1  = B2i + V;

    const dim3 cgrid(4096), cblk(256);
    const dim3 a8grid(8192), a8blk(256);
    const dim3 a1grid(8192), a1blk(256);

    cvt_x<<<8192, 256, 0, stream>>>(x, B2i);                                    // B2i = x (interleaved)

    // ---- adaptive block 1 (input x = B2i) ----
    conv_mfma<8, true, 0, _Float16><<<cgrid, cblk, 0, stream>>>(B2i, ac1_w1, ac1_b1, B1i);
    conv_mfma<27, false, 1, _Float16><<<cgrid, cblk, 0, stream>>>(B1i, ac1_w2, nullptr, Wb);
    adapt8<<<a8grid, a8blk, 0, stream>>>(B2i, Wb, B1i);
    adapt8<<<a8grid, a8blk, 0, stream>>>(B1i, Wb, B2i);
    adapt8<<<a8grid, a8blk, 0, stream>>>(B2i, Wb, B1i);                         // B1i = block1 out
    conv_mfma<8, false, 0, _Float16><<<cgrid, cblk, 0, stream>>>(B1i, mid_w, mid_b, B2i); // B2i = mid

    // ---- adaptive block 2 (input mid = B2i) ----
    conv_mfma<8, true, 0, _Float16><<<cgrid, cblk, 0, stream>>>(B2i, ac2_w1, ac2_b1, B1i);
    conv_mfma<27, false, 1, _Float16><<<cgrid, cblk, 0, stream>>>(B1i, ac2_w2, nullptr, Wb);
    adapt8<<<a8grid, a8blk, 0, stream>>>(B2i, Wb, B1i);
    adapt8<<<a8grid, a8blk, 0, stream>>>(B1i, Wb, B2i);
    adapt8<<<a8grid, a8blk, 0, stream>>>(B2i, Wb, B1i);                         // B1i = mid2

    // ---- block 3: weights from mid2 = B1i ----
    conv_mfma<8, true, 0, _Float16><<<cgrid, cblk, 0, stream>>>(B1i, ac3_w1, ac3_b1, B2i);
    conv_mfma<27, false, 1, _Float16><<<cgrid, cblk, 0, stream>>>(B2i, ac3_w2, nullptr, Wb);
    conv_mfma<1, false, 2, _Float16><<<cgrid, cblk, 0, stream>>>(B1i, out_w, out_b, F0);
    adapt1<_Float16><<<a1grid, a1blk, 0, stream>>>(F0, Wb, F1);
    adapt1<_Float16><<<a1grid, a1blk, 0, stream>>>(F1, Wb, F0);
    adapt1<float><<<a1grid, a1blk, 0, stream>>>(F0, Wb, outp);
}

// Round 9
// 881.715 us; speedup vs baseline: 1.4789x; 1.4789x over previous
//
#include <hip/hip_runtime.h>
#include <hip/hip_fp16.h>
#include <math.h>

#define WW 128
#define HH 128
#define DD 128
#define HW (WW * HH)
#define VOL (WW * HH * DD)

typedef _Float16 f16x8 __attribute__((ext_vector_type(8)));
typedef _Float16 f16x4 __attribute__((ext_vector_type(4)));
typedef _Float16 f16x2 __attribute__((ext_vector_type(2)));
typedef float f32x4 __attribute__((ext_vector_type(4)));
typedef int int4v __attribute__((ext_vector_type(4)));

__device__ __forceinline__ void stv(float* p, float v) { *p = v; }
__device__ __forceinline__ void stv(_Float16* p, float v) { *p = (_Float16)v; }

// ==========================================================================
// cvt_x: planar fp32 (8ch) -> channel-interleaved f16x8 [d][h][w][c8]
// ==========================================================================
__global__ __launch_bounds__(256) void cvt_x(const float* __restrict__ x,
                                             _Float16* __restrict__ xi)
{
    const size_t v = (size_t)blockIdx.x * 256 + threadIdx.x;
    f16x8 o;
#pragma unroll
    for (int c = 0; c < 8; ++c) o[c] = (_Float16)x[(size_t)c * VOL + v];
    *(f16x8*)(xi + v * 8) = o;
}

// ==========================================================================
// prepack_all: pack conv weights into exact MFMA A-fragment lane order.
// 16-layout (MT m-tiles of 16 rows): entry e=(mt*7+s)*64+lane holds
//   a[j] = wt[m*216 + j*27 + tap], m=mt*16+(lane&15), tap=s*4+(lane>>4).
// Sizes (halves): MT=1 -> 3584, MT=2 -> 7168.
// ==========================================================================
__global__ __launch_bounds__(256) void prepack_all(
    const float* __restrict__ w0, const float* __restrict__ w1,
    const float* __restrict__ w2, const float* __restrict__ w3,
    const float* __restrict__ w4, const float* __restrict__ w5,
    const float* __restrict__ w6, const float* __restrict__ w7,
    _Float16* __restrict__ pb)
{
    const int b = blockIdx.x;
    const float* src; int OC, MT; size_t off;
    switch (b) {
        case 0: src = w0; OC = 8;  MT = 1; off = 0;     break;
        case 1: src = w1; OC = 8;  MT = 1; off = 3584;  break;
        case 2: src = w2; OC = 8;  MT = 1; off = 7168;  break;
        case 3: src = w3; OC = 8;  MT = 1; off = 10752; break;
        case 4: src = w4; OC = 1;  MT = 1; off = 14336; break;
        case 5: src = w5; OC = 27; MT = 2; off = 17920; break;
        case 6: src = w6; OC = 27; MT = 2; off = 25088; break;
        default: src = w7; OC = 27; MT = 2; off = 32256; break;
    }
    const int total = MT * 448;
    for (int e = threadIdx.x; e < total; e += 256) {
        const int mt = e / 448, r = e % 448, s = r >> 6, lane = r & 63;
        const int m = mt * 16 + (lane & 15);
        const int tap = s * 4 + (lane >> 4);
        f16x8 a = {};
        if (tap < 27 && m < OC) {
#pragma unroll
            for (int j = 0; j < 8; ++j)
                a[j] = (_Float16)src[m * 216 + j * 27 + tap];
        }
        *(f16x8*)(pb + off + (size_t)e * 8) = a;
    }
}

// ==========================================================================
// conv_g: implicit-GEMM 3x3x3 conv via MFMA f16, NO LDS / NO BARRIERS.
// B-fragments load straight from global (channel-interleaved f16x8; one
// aligned 16B load per tap site); L1/L2 serve the 27x reuse. A-fragments
// come pre-packed (coalesced). Wave owns one (d,h) row = 8 n-tiles of 16.
// XCD swizzle: bid&7 selects a 16-deep d-slab for L2 locality.
// NOTE: input must be an interior workspace buffer — OOB halo reads are
// memory-safe (>=16MB margins) and are zeroed via select.
// OM: 0 = interleaved 8-ch out, 1 = [vox][32] L1-normed weight field,
//     2 = planar 1-ch out.
// ==========================================================================
template <int OC, bool RELU, int OM, typename TO>
__global__ __launch_bounds__(256) void conv_g(const _Float16* __restrict__ in,
                                              const _Float16* __restrict__ apack,
                                              const float* __restrict__ bias,
                                              TO* __restrict__ out)
{
    const int tid  = threadIdx.x;
    const int wid  = tid >> 6;
    const int lane = tid & 63;
    const int n    = lane & 15;
    const int quad = lane >> 4;

    const int bid = blockIdx.x;            // 4096 blocks x 4 waves = 16384 (d,h) rows
    const int idx = bid >> 3;
    const int d   = ((bid & 7) << 4) + (idx & 15);
    const int h   = ((idx >> 4) << 2) + wid;

    constexpr int MT = (OC > 16) ? 2 : 1;
    f16x8 afr[MT][7];
#pragma unroll
    for (int mt = 0; mt < MT; ++mt)
#pragma unroll
        for (int s = 0; s < 7; ++s)
            afr[mt][s] = *(const f16x8*)(apack + (size_t)((mt * 7 + s) * 64 + lane) * 8);

    // per-s geometry (quad-dependent)
    int voff[7], kwr[7];
    bool vok[7];
#pragma unroll
    for (int s = 0; s < 7; ++s) {
        int tap = s * 4 + quad;
        const bool pad = tap > 26;
        if (pad) tap = 26;
        const int kd = tap / 9, kh = (tap % 9) / 3, kw = tap % 3;
        const int gd = d + kd - 1, gh = h + kh - 1;
        vok[s] = !pad && ((unsigned)gd < (unsigned)DD) && ((unsigned)gh < (unsigned)HH);
        kwr[s] = kw - 1;
        voff[s] = gd * HW + gh * WW + (kw - 1);
    }

    float bv[MT][4];
#pragma unroll
    for (int mt = 0; mt < MT; ++mt)
#pragma unroll
        for (int r = 0; r < 4; ++r) {
            const int o = mt * 16 + quad * 4 + r;
            bv[mt][r] = ((OM != 1) && bias != nullptr && o < OC) ? bias[o] : 0.f;
        }

    const size_t rowbase = (size_t)d * HW + (size_t)h * WW;

#pragma unroll 2
    for (int wseg = 0; wseg < 8; ++wseg) {
        const int wv = wseg * 16 + n;
        // ---- load 7 B-fragments straight from global ----
        f16x8 bfr[7];
#pragma unroll
        for (int s = 0; s < 7; ++s) {
            const bool ok = vok[s] && ((unsigned)(wv + kwr[s]) < (unsigned)WW);
            f16x8 b = *(const f16x8*)(in + (ptrdiff_t)(voff[s] + wv) * 8);
            if (!ok) b = (f16x8){};
            bfr[s] = b;
        }
        // ---- MFMA chain ----
        f32x4 acc[MT];
#pragma unroll
        for (int mt = 0; mt < MT; ++mt) {
            acc[mt][0] = bv[mt][0]; acc[mt][1] = bv[mt][1];
            acc[mt][2] = bv[mt][2]; acc[mt][3] = bv[mt][3];
        }
#pragma unroll
        for (int s = 0; s < 7; ++s) {
            acc[0] = __builtin_amdgcn_mfma_f32_16x16x32_f16(afr[0][s], bfr[s], acc[0], 0, 0, 0);
            if (MT > 1)
                acc[1] = __builtin_amdgcn_mfma_f32_16x16x32_f16(afr[1][s], bfr[s], acc[1], 0, 0, 0);
        }
        const size_t vox = rowbase + wv;

        if (OM == 0) {
            if (quad < 2) {
                f16x4 o4;
#pragma unroll
                for (int r = 0; r < 4; ++r) {
                    float v = acc[0][r];
                    if (RELU) v = fmaxf(v, 0.f);
                    o4[r] = (_Float16)v;
                }
                *(f16x4*)((_Float16*)out + vox * 8 + quad * 4) = o4;
            }
        } else if (OM == 1) {
            float t0 = fabsf(acc[0][0]) + fabsf(acc[0][1]);
            float t1 = fabsf(acc[0][2]) + fabsf(acc[0][3]);
            float ssum;
            if (MT > 1) {
                float t2 = fabsf(acc[1][0]) + fabsf(acc[1][1]);
                float t3 = fabsf(acc[1][2]) + fabsf(acc[1][3]);
                ssum = (t0 + t1) + (t2 + t3);
            } else {
                ssum = t0 + t1;
            }
            ssum += __shfl_xor(ssum, 16);
            ssum += __shfl_xor(ssum, 32);
            const float inv = 1.0f / fmaxf(ssum, 1e-12f);
            int p[2][2];
#pragma unroll
            for (int mt = 0; mt < MT; ++mt)
#pragma unroll
                for (int rr = 0; rr < 2; ++rr) {
                    f16x2 t;
                    t[0] = (_Float16)(acc[mt][2 * rr] * inv);
                    t[1] = (_Float16)(acc[mt][2 * rr + 1] * inv);
                    p[mt][rr] = __builtin_bit_cast(int, t);
                }
            int4v wvv;
#pragma unroll
            for (int w = 0; w < 4; ++w) {
                const int sq = (2 * quad + (w >> 1)) & 3;
                const int bidx = ((sq << 4) | n) << 2;
                const int a0 = __builtin_amdgcn_ds_bpermute(bidx, p[0][w & 1]);
                const int a1 = __builtin_amdgcn_ds_bpermute(bidx, p[1][w & 1]);
                wvv[w] = (quad < 2) ? a0 : a1;
            }
            *(int4v*)((_Float16*)out + (vox << 5) + (quad << 3)) = wvv;
        } else { // OM == 2, OC = 1 planar
            if (quad == 0) {
                float v = acc[0][0];
                if (RELU) v = fmaxf(v, 0.f);
                stv((TO*)out + vox, v);
            }
        }
    }
}

// ==========================================================================
// adapt8 (R6 best form — 1 voxel/thread, fully coalesced): per-voxel 27-tap
// weights [vox][32] fp16, 8 interleaved channels.
// ==========================================================================
__global__ __launch_bounds__(256) void adapt8(const _Float16* __restrict__ in,
                                              const _Float16* __restrict__ wn,
                                              _Float16* __restrict__ out)
{
    const int tid = threadIdx.x;
    const int bid = blockIdx.x;            // 8192 = 128 d x 64 h-pairs
    const int d = bid >> 6;
    const int h = ((bid & 63) << 1) + (tid >> 7);
    const int w = tid & 127;
    const size_t vox = (size_t)d * HW + (size_t)h * WW + w;

    const f16x8* wrow = (const f16x8*)(wn + (vox << 5));
    f16x8 wkv[4];
#pragma unroll
    for (int j = 0; j < 4; ++j) wkv[j] = wrow[j];

    float acc[8] = {0.f, 0.f, 0.f, 0.f, 0.f, 0.f, 0.f, 0.f};
#pragma unroll
    for (int kd = 0; kd < 3; ++kd) {
        const int gd = d + kd - 1;
#pragma unroll
        for (int kh = 0; kh < 3; ++kh) {
            const int gh = h + kh - 1;
#pragma unroll
            for (int kw = 0; kw < 3; ++kw) {
                const int gw = w + kw - 1;
                const bool ok = ((unsigned)gd < (unsigned)DD) &&
                                ((unsigned)gh < (unsigned)HH) &&
                                ((unsigned)gw < (unsigned)WW);
                f16x8 xv = {};
                if (ok)
                    xv = *(const f16x8*)(in + ((size_t)gd * HW + (size_t)gh * WW + gw) * 8);
                const int t = kd * 9 + kh * 3 + kw;
                const float wvv = (float)wkv[t >> 3][t & 7];
#pragma unroll
                for (int c = 0; c < 8; ++c) acc[c] += wvv * (float)xv[c];
            }
        }
    }
    f16x8 o;
#pragma unroll
    for (int c = 0; c < 8; ++c) o[c] = (_Float16)acc[c];
    *(f16x8*)(out + vox * 8) = o;
}

// ==========================================================================
// adapt1: 1 channel, planar in/out; weights [vox][32]. Thread = 1 voxel.
// ==========================================================================
template <typename TOUT>
__global__ __launch_bounds__(256) void adapt1(const _Float16* __restrict__ in,
                                              const _Float16* __restrict__ wn,
                                              TOUT* __restrict__ out)
{
    const size_t vox = (size_t)blockIdx.x * 256 + threadIdx.x;
    const int w = (int)(vox & 127);
    const int h = (int)((vox >> 7) & 127);
    const int d = (int)(vox >> 14);

    const f16x8* wrow = (const f16x8*)(wn + (vox << 5));
    f16x8 wkv[4];
#pragma unroll
    for (int j = 0; j < 4; ++j) wkv[j] = wrow[j];

    float acc = 0.f;
#pragma unroll
    for (int kd = 0; kd < 3; ++kd) {
        const int gd = d + kd - 1;
#pragma unroll
        for (int kh = 0; kh < 3; ++kh) {
            const int gh = h + kh - 1;
#pragma unroll
            for (int kw = 0; kw < 3; ++kw) {
                const int gw = w + kw - 1;
                const bool ok = ((unsigned)gd < (unsigned)DD) &&
                                ((unsigned)gh < (unsigned)HH) &&
                                ((unsigned)gw < (unsigned)WW);
                float xv = 0.f;
                if (ok)
                    xv = (float)in[(size_t)gd * HW + (size_t)gh * WW + gw];
                const int t = kd * 9 + kh * 3 + kw;
                acc += (float)wkv[t >> 3][t & 7] * xv;
            }
        }
    }
    stv(out + vox, acc);
}

extern "C" void kernel_launch(void* const* d_in, const int* in_sizes, int n_in,
                              void* d_out, int out_size, void* d_ws, size_t ws_size,
                              hipStream_t stream)
{
    (void)in_sizes; (void)n_in; (void)out_size; (void)ws_size;

    const float* x      = (const float*)d_in[0];
    const float* ac1_w1 = (const float*)d_in[1];
    const float* ac1_b1 = (const float*)d_in[2];
    const float* ac1_w2 = (const float*)d_in[3];
    const float* ac2_w1 = (const float*)d_in[4];
    const float* ac2_b1 = (const float*)d_in[5];
    const float* ac2_w2 = (const float*)d_in[6];
    const float* ac3_w1 = (const float*)d_in[7];
    const float* ac3_b1 = (const float*)d_in[8];
    const float* ac3_w2 = (const float*)d_in[9];
    const float* mid_w  = (const float*)d_in[10];
    const float* mid_b  = (const float*)d_in[11];
    const float* out_w  = (const float*)d_in[12];
    const float* out_b  = (const float*)d_in[13];
    float* outp = (float*)d_out;

    // fp16 scratch, 192 MB + 77 KB packs:
    // Wb = [vox][32] weight field (32V) | B1i = 8V interleaved | B2i = 8V | packs
    const size_t V = (size_t)VOL;
    _Float16* Wb  = (_Float16*)d_ws;
    _Float16* B1i = Wb + 32 * V;
    _Float16* B2i = B1i + 8 * V;
    _Float16* F0  = B2i;        // block-3 planar 1-ch ping-pong (B2i free there)
    _Float16* F1  = B2i + V;
    _Float16* PB  = B2i + 8 * V;   // pack base (77 KB)

    _Float16* pk_ac1w1 = PB + 0;
    _Float16* pk_ac2w1 = PB + 3584;
    _Float16* pk_ac3w1 = PB + 7168;
    _Float16* pk_midw  = PB + 10752;
    _Float16* pk_outw  = PB + 14336;
    _Float16* pk_ac1w2 = PB + 17920;
    _Float16* pk_ac2w2 = PB + 25088;
    _Float16* pk_ac3w2 = PB + 32256;

    const dim3 cgrid(4096), cblk(256);
    const dim3 a8grid(8192), a8blk(256);
    const dim3 a1grid(8192), a1blk(256);

    prepack_all<<<8, 256, 0, stream>>>(ac1_w1, ac2_w1, ac3_w1, mid_w, out_w,
                                       ac1_w2, ac2_w2, ac3_w2, PB);
    cvt_x<<<8192, 256, 0, stream>>>(x, B2i);                                   // B2i = x

    // ---- adaptive block 1 (input x = B2i) ----
    conv_g<8, true, 0, _Float16><<<cgrid, cblk, 0, stream>>>(B2i, pk_ac1w1, ac1_b1, B1i);
    conv_g<27, false, 1, _Float16><<<cgrid, cblk, 0, stream>>>(B1i, pk_ac1w2, nullptr, Wb);
    adapt8<<<a8grid, a8blk, 0, stream>>>(B2i, Wb, B1i);
    adapt8<<<a8grid, a8blk, 0, stream>>>(B1i, Wb, B2i);
    adapt8<<<a8grid, a8blk, 0, stream>>>(B2i, Wb, B1i);                        // B1i = block1 out
    conv_g<8, false, 0, _Float16><<<cgrid, cblk, 0, stream>>>(B1i, pk_midw, mid_b, B2i); // B2i = mid

    // ---- adaptive block 2 (input mid = B2i) ----
    conv_g<8, true, 0, _Float16><<<cgrid, cblk, 0, stream>>>(B2i, pk_ac2w1, ac2_b1, B1i);
    conv_g<27, false, 1, _Float16><<<cgrid, cblk, 0, stream>>>(B1i, pk_ac2w2, nullptr, Wb);
    adapt8<<<a8grid, a8blk, 0, stream>>>(B2i, Wb, B1i);
    adapt8<<<a8grid, a8blk, 0, stream>>>(B1i, Wb, B2i);
    adapt8<<<a8grid, a8blk, 0, stream>>>(B2i, Wb, B1i);                        // B1i = mid2

    // ---- block 3: weights from mid2 = B1i ----
    conv_g<8, true, 0, _Float16><<<cgrid, cblk, 0, stream>>>(B1i, pk_ac3w1, ac3_b1, B2i);
    conv_g<27, false, 1, _Float16><<<cgrid, cblk, 0, stream>>>(B2i, pk_ac3w2, nullptr, Wb);
    conv_g<1, false, 2, _Float16><<<cgrid, cblk, 0, stream>>>(B1i, pk_outw, out_b, F0);
    adapt1<_Float16><<<a1grid, a1blk, 0, stream>>>(F0, Wb, F1);
    adapt1<_Float16><<<a1grid, a1blk, 0, stream>>>(F1, Wb, F0);
    adapt1<float><<<a1grid, a1blk, 0, stream>>>(F0, Wb, outp);
}

// Round 10
// 875.344 us; speedup vs baseline: 1.4897x; 1.0073x over previous
//
#include <hip/hip_runtime.h>
#include <hip/hip_fp16.h>
#include <math.h>

#define WW 128
#define HH 128
#define DD 128
#define HW (WW * HH)
#define VOL (WW * HH * DD)
// padded (halo) geometry: 130^3, interior voxel (d,h,w) -> padded (d+1,h+1,w+1)
#define PW 130
#define PHW (130 * 130)
#define PVOL (130 * 130 * 130)

typedef _Float16 f16x8 __attribute__((ext_vector_type(8)));
typedef _Float16 f16x4 __attribute__((ext_vector_type(4)));
typedef _Float16 f16x2 __attribute__((ext_vector_type(2)));
typedef float f32x4 __attribute__((ext_vector_type(4)));
typedef int int4v __attribute__((ext_vector_type(4)));

__device__ __forceinline__ void stv(float* p, float v) { *p = v; }
__device__ __forceinline__ void stv(_Float16* p, float v) { *p = (_Float16)v; }

// ==========================================================================
// zero_ws: zero the padded activation region (B1i|B2i|F0|F1, contiguous).
// Pads stay zero afterwards because all kernels write interior-only.
// ==========================================================================
__global__ __launch_bounds__(256) void zero_ws(_Float16* __restrict__ p, long n8)
{
    const long stride = (long)gridDim.x * 256;
    for (long j = (long)blockIdx.x * 256 + threadIdx.x; j < n8; j += stride)
        *(f16x8*)(p + j * 8) = (f16x8){};
}

// ==========================================================================
// cvt_x: planar fp32 (8ch) -> channel-interleaved f16x8, PADDED layout
// ==========================================================================
__global__ __launch_bounds__(256) void cvt_x(const float* __restrict__ x,
                                             _Float16* __restrict__ xi)
{
    const size_t v = (size_t)blockIdx.x * 256 + threadIdx.x;
    const int d = (int)(v >> 14), h = (int)((v >> 7) & 127), w = (int)(v & 127);
    f16x8 o;
#pragma unroll
    for (int c = 0; c < 8; ++c) o[c] = (_Float16)x[(size_t)c * VOL + v];
    *(f16x8*)(xi + ((size_t)(d + 1) * PHW + (size_t)(h + 1) * PW + (w + 1)) * 8) = o;
}

// ==========================================================================
// prepack_all: pack conv weights into exact MFMA A-fragment lane order.
// entry e=(mt*7+s)*64+lane holds a[j] = wt[m*216 + j*27 + tap],
//   m=mt*16+(lane&15), tap=s*4+(lane>>4). MT=1 -> 3584 halves, MT=2 -> 7168.
// ==========================================================================
__global__ __launch_bounds__(256) void prepack_all(
    const float* __restrict__ w0, const float* __restrict__ w1,
    const float* __restrict__ w2, const float* __restrict__ w3,
    const float* __restrict__ w4, const float* __restrict__ w5,
    const float* __restrict__ w6, const float* __restrict__ w7,
    _Float16* __restrict__ pb)
{
    const int b = blockIdx.x;
    const float* src; int OC, MT; size_t off;
    switch (b) {
        case 0: src = w0; OC = 8;  MT = 1; off = 0;     break;
        case 1: src = w1; OC = 8;  MT = 1; off = 3584;  break;
        case 2: src = w2; OC = 8;  MT = 1; off = 7168;  break;
        case 3: src = w3; OC = 8;  MT = 1; off = 10752; break;
        case 4: src = w4; OC = 1;  MT = 1; off = 14336; break;
        case 5: src = w5; OC = 27; MT = 2; off = 17920; break;
        case 6: src = w6; OC = 27; MT = 2; off = 25088; break;
        default: src = w7; OC = 27; MT = 2; off = 32256; break;
    }
    const int total = MT * 448;
    for (int e = threadIdx.x; e < total; e += 256) {
        const int mt = e / 448, r = e % 448, s = r >> 6, lane = r & 63;
        const int m = mt * 16 + (lane & 15);
        const int tap = s * 4 + (lane >> 4);
        f16x8 a = {};
        if (tap < 27 && m < OC) {
#pragma unroll
            for (int j = 0; j < 8; ++j)
                a[j] = (_Float16)src[m * 216 + j * 27 + tap];
        }
        *(f16x8*)(pb + off + (size_t)e * 8) = a;
    }
}

// ==========================================================================
// conv_g: implicit-GEMM 3x3x3 conv via MFMA f16, NO LDS / NO BARRIERS /
// NO BOUNDS CHECKS (padded input). B-fragments load straight from global;
// L1/L2 serve the 27x reuse. A-fragments pre-packed. Wave owns one (d,h)
// row = 8 n-tiles of 16 voxels. XCD swizzle: bid&7 -> 16-deep d-slab.
// OM: 0 = padded interleaved 8-ch out, 1 = unpadded [vox][32] L1-normed
//     weight field, 2 = padded planar 1-ch out.
// ==========================================================================
template <int OC, bool RELU, int OM, typename TO>
__global__ __launch_bounds__(256) void conv_g(const _Float16* __restrict__ in,
                                              const _Float16* __restrict__ apack,
                                              const float* __restrict__ bias,
                                              TO* __restrict__ out)
{
    const int tid  = threadIdx.x;
    const int wid  = tid >> 6;
    const int lane = tid & 63;
    const int n    = lane & 15;
    const int quad = lane >> 4;

    const int bid = blockIdx.x;            // 4096 blocks x 4 waves = 16384 (d,h) rows
    const int idx = bid >> 3;
    const int d   = ((bid & 7) << 4) + (idx & 15);
    const int h   = ((idx >> 4) << 2) + wid;

    constexpr int MT = (OC > 16) ? 2 : 1;
    f16x8 afr[MT][7];
#pragma unroll
    for (int mt = 0; mt < MT; ++mt)
#pragma unroll
        for (int s = 0; s < 7; ++s)
            afr[mt][s] = *(const f16x8*)(apack + (size_t)((mt * 7 + s) * 64 + lane) * 8);

    // per-s geometry (quad-dependent), padded coords: neighbor = (d+kd, h+kh, w+kw)
    int voff[7];
#pragma unroll
    for (int s = 0; s < 7; ++s) {
        int tap = s * 4 + quad;
        if (tap > 26) tap = 26;            // A is zero there; address just valid
        const int kd = tap / 9, kh = (tap % 9) / 3, kw = tap % 3;
        voff[s] = (d + kd) * PHW + (h + kh) * PW + kw;
    }

    float bv[MT][4];
#pragma unroll
    for (int mt = 0; mt < MT; ++mt)
#pragma unroll
        for (int r = 0; r < 4; ++r) {
            const int o = mt * 16 + quad * 4 + r;
            bv[mt][r] = ((OM != 1) && bias != nullptr && o < OC) ? bias[o] : 0.f;
        }

#pragma unroll 2
    for (int wseg = 0; wseg < 8; ++wseg) {
        const int wv = wseg * 16 + n;
        // ---- 7 unconditional B-fragment loads straight from global ----
        f16x8 bfr[7];
#pragma unroll
        for (int s = 0; s < 7; ++s)
            bfr[s] = *(const f16x8*)(in + (size_t)(voff[s] + wv) * 8);
        // ---- MFMA chain ----
        f32x4 acc[MT];
#pragma unroll
        for (int mt = 0; mt < MT; ++mt) {
            acc[mt][0] = bv[mt][0]; acc[mt][1] = bv[mt][1];
            acc[mt][2] = bv[mt][2]; acc[mt][3] = bv[mt][3];
        }
#pragma unroll
        for (int s = 0; s < 7; ++s) {
            acc[0] = __builtin_amdgcn_mfma_f32_16x16x32_f16(afr[0][s], bfr[s], acc[0], 0, 0, 0);
            if (MT > 1)
                acc[1] = __builtin_amdgcn_mfma_f32_16x16x32_f16(afr[1][s], bfr[s], acc[1], 0, 0, 0);
        }

        if (OM == 0) {
            if (quad < 2) {
                const size_t pvox = (size_t)(d + 1) * PHW + (size_t)(h + 1) * PW + 1 + wv;
                f16x4 o4;
#pragma unroll
                for (int r = 0; r < 4; ++r) {
                    float v = acc[0][r];
                    if (RELU) v = fmaxf(v, 0.f);
                    o4[r] = (_Float16)v;
                }
                *(f16x4*)((_Float16*)out + pvox * 8 + quad * 4) = o4;
            }
        } else if (OM == 1) {
            const size_t vox = (size_t)d * HW + (size_t)h * WW + wv;   // unpadded
            float t0 = fabsf(acc[0][0]) + fabsf(acc[0][1]);
            float t1 = fabsf(acc[0][2]) + fabsf(acc[0][3]);
            float ssum;
            if (MT > 1) {
                float t2 = fabsf(acc[1][0]) + fabsf(acc[1][1]);
                float t3 = fabsf(acc[1][2]) + fabsf(acc[1][3]);
                ssum = (t0 + t1) + (t2 + t3);
            } else {
                ssum = t0 + t1;
            }
            ssum += __shfl_xor(ssum, 16);
            ssum += __shfl_xor(ssum, 32);
            const float inv = 1.0f / fmaxf(ssum, 1e-12f);
            int p[2][2];
#pragma unroll
            for (int mt = 0; mt < MT; ++mt)
#pragma unroll
                for (int rr = 0; rr < 2; ++rr) {
                    f16x2 t;
                    t[0] = (_Float16)(acc[mt][2 * rr] * inv);
                    t[1] = (_Float16)(acc[mt][2 * rr + 1] * inv);
                    p[mt][rr] = __builtin_bit_cast(int, t);
                }
            int4v wvv;
#pragma unroll
            for (int w = 0; w < 4; ++w) {
                const int sq = (2 * quad + (w >> 1)) & 3;
                const int bidx = ((sq << 4) | n) << 2;
                const int a0 = __builtin_amdgcn_ds_bpermute(bidx, p[0][w & 1]);
                const int a1 = __builtin_amdgcn_ds_bpermute(bidx, p[1][w & 1]);
                wvv[w] = (quad < 2) ? a0 : a1;
            }
            *(int4v*)((_Float16*)out + (vox << 5) + (quad << 3)) = wvv;
        } else { // OM == 2, OC = 1, padded planar out
            if (quad == 0) {
                const size_t pvox = (size_t)(d + 1) * PHW + (size_t)(h + 1) * PW + 1 + wv;
                float v = acc[0][0];
                if (RELU) v = fmaxf(v, 0.f);
                stv((TO*)out + pvox, v);
            }
        }
    }
}

// ==========================================================================
// adapt8: per-voxel 27-tap weights (unpadded [vox][32] fp16), 8 interleaved
// channels, PADDED in/out — no bounds checks, 27 unconditional f16x8 loads.
// ==========================================================================
__global__ __launch_bounds__(256) void adapt8(const _Float16* __restrict__ in,
                                              const _Float16* __restrict__ wn,
                                              _Float16* __restrict__ out)
{
    const int tid = threadIdx.x;
    const int bid = blockIdx.x;            // 8192 = 128 d x 64 h-pairs
    const int d = bid >> 6;
    const int h = ((bid & 63) << 1) + (tid >> 7);
    const int w = tid & 127;
    const size_t vox = (size_t)d * HW + (size_t)h * WW + w;   // unpadded (weights)

    const f16x8* wrow = (const f16x8*)(wn + (vox << 5));
    f16x8 wkv[4];
#pragma unroll
    for (int j = 0; j < 4; ++j) wkv[j] = wrow[j];

    float acc[8] = {0.f, 0.f, 0.f, 0.f, 0.f, 0.f, 0.f, 0.f};
#pragma unroll
    for (int kd = 0; kd < 3; ++kd) {
#pragma unroll
        for (int kh = 0; kh < 3; ++kh) {
            const _Float16* rp = in + ((size_t)(d + kd) * PHW + (size_t)(h + kh) * PW + w) * 8;
#pragma unroll
            for (int kw = 0; kw < 3; ++kw) {
                const f16x8 xv = *(const f16x8*)(rp + (size_t)kw * 8);
                const int t = kd * 9 + kh * 3 + kw;
                const float wvv = (float)wkv[t >> 3][t & 7];
#pragma unroll
                for (int c = 0; c < 8; ++c) acc[c] += wvv * (float)xv[c];
            }
        }
    }
    f16x8 o;
#pragma unroll
    for (int c = 0; c < 8; ++c) o[c] = (_Float16)acc[c];
    *(f16x8*)(out + ((size_t)(d + 1) * PHW + (size_t)(h + 1) * PW + (w + 1)) * 8) = o;
}

// ==========================================================================
// adapt1: 1 channel, PADDED planar f16 in; weights unpadded [vox][32].
// PADOUT: padded f16 out (intermediate) or unpadded out (final).
// ==========================================================================
template <bool PADOUT, typename TOUT>
__global__ __launch_bounds__(256) void adapt1(const _Float16* __restrict__ in,
                                              const _Float16* __restrict__ wn,
                                              TOUT* __restrict__ out)
{
    const size_t vox = (size_t)blockIdx.x * 256 + threadIdx.x;
    const int w = (int)(vox & 127);
    const int h = (int)((vox >> 7) & 127);
    const int d = (int)(vox >> 14);

    const f16x8* wrow = (const f16x8*)(wn + (vox << 5));
    f16x8 wkv[4];
#pragma unroll
    for (int j = 0; j < 4; ++j) wkv[j] = wrow[j];

    float acc = 0.f;
#pragma unroll
    for (int kd = 0; kd < 3; ++kd) {
#pragma unroll
        for (int kh = 0; kh < 3; ++kh) {
            const _Float16* rp = in + (size_t)(d + kd) * PHW + (size_t)(h + kh) * PW + w;
#pragma unroll
            for (int kw = 0; kw < 3; ++kw) {
                const int t = kd * 9 + kh * 3 + kw;
                acc += (float)wkv[t >> 3][t & 7] * (float)rp[kw];
            }
        }
    }
    if (PADOUT)
        stv(out + (size_t)(d + 1) * PHW + (size_t)(h + 1) * PW + (w + 1), acc);
    else
        stv(out + vox, acc);
}

extern "C" void kernel_launch(void* const* d_in, const int* in_sizes, int n_in,
                              void* d_out, int out_size, void* d_ws, size_t ws_size,
                              hipStream_t stream)
{
    (void)in_sizes; (void)n_in; (void)out_size; (void)ws_size;

    const float* x      = (const float*)d_in[0];
    const float* ac1_w1 = (const float*)d_in[1];
    const float* ac1_b1 = (const float*)d_in[2];
    const float* ac1_w2 = (const float*)d_in[3];
    const float* ac2_w1 = (const float*)d_in[4];
    const float* ac2_b1 = (const float*)d_in[5];
    const float* ac2_w2 = (const float*)d_in[6];
    const float* ac3_w1 = (const float*)d_in[7];
    const float* ac3_b1 = (const float*)d_in[8];
    const float* ac3_w2 = (const float*)d_in[9];
    const float* mid_w  = (const float*)d_in[10];
    const float* mid_b  = (const float*)d_in[11];
    const float* out_w  = (const float*)d_in[12];
    const float* out_b  = (const float*)d_in[13];
    float* outp = (float*)d_out;

    // fp16 scratch (213 MB, ws >= 236 MB per R2 forensics):
    // Wb [vox][32] (32V) | B1i 8*PVOL padded | B2i 8*PVOL padded
    // | F0 PVOL padded planar | F1 PVOL | packs
    const size_t V = (size_t)VOL;
    _Float16* Wb  = (_Float16*)d_ws;
    _Float16* B1i = Wb + 32 * V;
    _Float16* B2i = B1i + (size_t)8 * PVOL;
    _Float16* F0  = B2i + (size_t)8 * PVOL;
    _Float16* F1  = F0 + (size_t)PVOL;
    _Float16* PB  = F1 + (size_t)PVOL;

    _Float16* pk_ac1w1 = PB + 0;
    _Float16* pk_ac2w1 = PB + 3584;
    _Float16* pk_ac3w1 = PB + 7168;
    _Float16* pk_midw  = PB + 10752;
    _Float16* pk_outw  = PB + 14336;
    _Float16* pk_ac1w2 = PB + 17920;
    _Float16* pk_ac2w2 = PB + 25088;
    _Float16* pk_ac3w2 = PB + 32256;

    const dim3 cgrid(4096), cblk(256);
    const dim3 a8grid(8192), a8blk(256);
    const dim3 a1grid(8192), a1blk(256);

    // zero padded region (B1i..F1 contiguous): 18*PVOL halves
    zero_ws<<<8192, 256, 0, stream>>>(B1i, (long)(18LL * PVOL / 8));
    prepack_all<<<8, 256, 0, stream>>>(ac1_w1, ac2_w1, ac3_w1, mid_w, out_w,
                                       ac1_w2, ac2_w2, ac3_w2, PB);
    cvt_x<<<8192, 256, 0, stream>>>(x, B2i);                                   // B2i = x

    // ---- adaptive block 1 (input x = B2i) ----
    conv_g<8, true, 0, _Float16><<<cgrid, cblk, 0, stream>>>(B2i, pk_ac1w1, ac1_b1, B1i);
    conv_g<27, false, 1, _Float16><<<cgrid, cblk, 0, stream>>>(B1i, pk_ac1w2, nullptr, Wb);
    adapt8<<<a8grid, a8blk, 0, stream>>>(B2i, Wb, B1i);
    adapt8<<<a8grid, a8blk, 0, stream>>>(B1i, Wb, B2i);
    adapt8<<<a8grid, a8blk, 0, stream>>>(B2i, Wb, B1i);                        // B1i = block1 out
    conv_g<8, false, 0, _Float16><<<cgrid, cblk, 0, stream>>>(B1i, pk_midw, mid_b, B2i); // B2i = mid

    // ---- adaptive block 2 (input mid = B2i) ----
    conv_g<8, true, 0, _Float16><<<cgrid, cblk, 0, stream>>>(B2i, pk_ac2w1, ac2_b1, B1i);
    conv_g<27, false, 1, _Float16><<<cgrid, cblk, 0, stream>>>(B1i, pk_ac2w2, nullptr, Wb);
    adapt8<<<a8grid, a8blk, 0, stream>>>(B2i, Wb, B1i);
    adapt8<<<a8grid, a8blk, 0, stream>>>(B1i, Wb, B2i);
    adapt8<<<a8grid, a8blk, 0, stream>>>(B2i, Wb, B1i);                        // B1i = mid2

    // ---- block 3: weights from mid2 = B1i ----
    conv_g<8, true, 0, _Float16><<<cgrid, cblk, 0, stream>>>(B1i, pk_ac3w1, ac3_b1, B2i);
    conv_g<27, false, 1, _Float16><<<cgrid, cblk, 0, stream>>>(B2i, pk_ac3w2, nullptr, Wb);
    conv_g<1, false, 2, _Float16><<<cgrid, cblk, 0, stream>>>(B1i, pk_outw, out_b, F0);
    adapt1<true, _Float16><<<a1grid, a1blk, 0, stream>>>(F0, Wb, F1);
    adapt1<true, _Float16><<<a1grid, a1blk, 0, stream>>>(F1, Wb, F0);
    adapt1<false, float><<<a1grid, a1blk, 0, stream>>>(F0, Wb, outp);
}

// Round 11
// 828.648 us; speedup vs baseline: 1.5737x; 1.0564x over previous
//
#include <hip/hip_runtime.h>
#include <hip/hip_fp16.h>
#include <math.h>

#define WW 128
#define HH 128
#define DD 128
#define HW (WW * HH)
#define VOL (WW * HH * DD)
// padded (halo) geometry: 130^3, interior voxel (d,h,w) -> padded (d+1,h+1,w+1)
#define PW 130
#define PHW (130 * 130)
#define PVOL (130 * 130 * 130)
#define NSHELL 99848   // 130^3 - 128^3

typedef _Float16 f16x8 __attribute__((ext_vector_type(8)));
typedef _Float16 f16x4 __attribute__((ext_vector_type(4)));
typedef _Float16 f16x2 __attribute__((ext_vector_type(2)));
typedef float f32x4 __attribute__((ext_vector_type(4)));
typedef float f32x16 __attribute__((ext_vector_type(16)));
typedef int int4v __attribute__((ext_vector_type(4)));

__device__ __forceinline__ void stv(float* p, float v) { *p = v; }
__device__ __forceinline__ void stv(_Float16* p, float v) { *p = (_Float16)v; }

// weight-field slot for tap m (conv27 stores in MFMA 32x32 C-layout order):
// row m held by lane-half (m>>2)&1, reg r with r&3=m&3, r>>2=m>>3.
#define WPOS(m) ((((m) >> 2) & 1) * 16 + ((m) >> 3) * 4 + ((m) & 3))

// ==========================================================================
// zero_shell: zero only the 1-voxel pad shell of a padded volume.
// NCH=8: interleaved f16x8 sites; NCH=1: planar halves.
// ==========================================================================
template <int NCH>
__global__ __launch_bounds__(256) void zero_shell(_Float16* __restrict__ p)
{
    const int t = blockIdx.x * 256 + threadIdx.x;
    if (t >= NSHELL) return;
    int d, h, w;
    if (t < 33800)      { d = (t < 16900) ? 0 : 129; int r = t % 16900; h = r / 130; w = r % 130; }
    else if (t < 67080) { int r = t - 33800; h = (r < 16640) ? 0 : 129; int q = r % 16640; d = 1 + q / 130; w = q % 130; }
    else                { int r = t - 67080; w = (r < 16384) ? 0 : 129; int q = r % 16384; d = 1 + q / 128; h = 1 + q % 128; }
    const size_t site = (size_t)d * PHW + (size_t)h * PW + w;
    if (NCH == 8) *(f16x8*)(p + site * 8) = (f16x8){};
    else          p[site] = (_Float16)0.f;
}

// ==========================================================================
// cvt_x: planar fp32 (8ch) -> channel-interleaved f16x8, PADDED layout
// ==========================================================================
__global__ __launch_bounds__(256) void cvt_x(const float* __restrict__ x,
                                             _Float16* __restrict__ xi)
{
    const size_t v = (size_t)blockIdx.x * 256 + threadIdx.x;
    const int d = (int)(v >> 14), h = (int)((v >> 7) & 127), w = (int)(v & 127);
    f16x8 o;
#pragma unroll
    for (int c = 0; c < 8; ++c) o[c] = (_Float16)x[(size_t)c * VOL + v];
    *(f16x8*)(xi + ((size_t)(d + 1) * PHW + (size_t)(h + 1) * PW + (w + 1)) * 8) = o;
}

// ==========================================================================
// prepack_all: pack conv weights into exact MFMA A-fragment lane order.
// blocks 0-4 (16x16 layout, OC<=16): entry e=s*64+lane, s=0..6:
//   a[j] = wt[m*216 + j*27 + tap], m=lane&15, tap=s*4+(lane>>4)
// blocks 5-7 (32x32 layout, OC=27): entry e=s*64+lane, s=0..13:
//   a[j] = wt[m*216 + j*27 + tap], m=lane&31, tap=2*s+(lane>>5)
// ==========================================================================
__global__ __launch_bounds__(256) void prepack_all(
    const float* __restrict__ w0, const float* __restrict__ w1,
    const float* __restrict__ w2, const float* __restrict__ w3,
    const float* __restrict__ w4, const float* __restrict__ w5,
    const float* __restrict__ w6, const float* __restrict__ w7,
    _Float16* __restrict__ pb)
{
    const int b = blockIdx.x;
    const float* src; int OC; size_t off;
    switch (b) {
        case 0: src = w0; OC = 8;  off = 0;     break;
        case 1: src = w1; OC = 8;  off = 3584;  break;
        case 2: src = w2; OC = 8;  off = 7168;  break;
        case 3: src = w3; OC = 8;  off = 10752; break;
        case 4: src = w4; OC = 1;  off = 14336; break;
        case 5: src = w5; OC = 27; off = 17920; break;
        case 6: src = w6; OC = 27; off = 25088; break;
        default: src = w7; OC = 27; off = 32256; break;
    }
    const bool big = (b >= 5);
    const int total = big ? 896 : 448;
    for (int e = threadIdx.x; e < total; e += 256) {
        const int s = e >> 6, lane = e & 63;
        const int m   = big ? (lane & 31) : (lane & 15);
        const int tap = big ? (2 * s + (lane >> 5)) : (s * 4 + (lane >> 4));
        f16x8 a = {};
        if (tap < 27 && m < OC) {
#pragma unroll
            for (int j = 0; j < 8; ++j)
                a[j] = (_Float16)src[m * 216 + j * 27 + tap];
        }
        *(f16x8*)(pb + off + (size_t)e * 8) = a;
    }
}

// ==========================================================================
// conv_g: implicit-GEMM 3x3x3 conv via MFMA 16x16x32 f16, OC<=16.
// No LDS / no barriers / no bounds checks (padded input). Wave owns one
// (d,h) row = 8 n-tiles of 16 voxels. XCD swizzle: bid&7 -> 16-deep d-slab.
// OM: 0 = padded interleaved 8-ch out, 2 = padded planar 1-ch out.
// ==========================================================================
template <int OC, bool RELU, int OM, typename TO>
__global__ __launch_bounds__(256) void conv_g(const _Float16* __restrict__ in,
                                              const _Float16* __restrict__ apack,
                                              const float* __restrict__ bias,
                                              TO* __restrict__ out)
{
    const int tid  = threadIdx.x;
    const int wid  = tid >> 6;
    const int lane = tid & 63;
    const int n    = lane & 15;
    const int quad = lane >> 4;

    const int bid = blockIdx.x;            // 4096 blocks x 4 waves = 16384 (d,h) rows
    const int idx = bid >> 3;
    const int d   = ((bid & 7) << 4) + (idx & 15);
    const int h   = ((idx >> 4) << 2) + wid;

    f16x8 afr[7];
#pragma unroll
    for (int s = 0; s < 7; ++s)
        afr[s] = *(const f16x8*)(apack + (size_t)(s * 64 + lane) * 8);

    int voff[7];
#pragma unroll
    for (int s = 0; s < 7; ++s) {
        int tap = s * 4 + quad;
        if (tap > 26) tap = 26;            // A is zero there; address just valid
        const int kd = tap / 9, kh = (tap % 9) / 3, kw = tap % 3;
        voff[s] = (d + kd) * PHW + (h + kh) * PW + kw;
    }

    float bv[4];
#pragma unroll
    for (int r = 0; r < 4; ++r) {
        const int o = quad * 4 + r;
        bv[r] = (bias != nullptr && o < OC) ? bias[o] : 0.f;
    }

#pragma unroll 2
    for (int wseg = 0; wseg < 8; ++wseg) {
        const int wv = wseg * 16 + n;
        f16x8 bfr[7];
#pragma unroll
        for (int s = 0; s < 7; ++s)
            bfr[s] = *(const f16x8*)(in + (size_t)(voff[s] + wv) * 8);
        f32x4 acc;
        acc[0] = bv[0]; acc[1] = bv[1]; acc[2] = bv[2]; acc[3] = bv[3];
#pragma unroll
        for (int s = 0; s < 7; ++s)
            acc = __builtin_amdgcn_mfma_f32_16x16x32_f16(afr[s], bfr[s], acc, 0, 0, 0);

        if (OM == 0) {
            if (quad < 2) {
                const size_t pvox = (size_t)(d + 1) * PHW + (size_t)(h + 1) * PW + 1 + wv;
                f16x4 o4;
#pragma unroll
                for (int r = 0; r < 4; ++r) {
                    float v = acc[r];
                    if (RELU) v = fmaxf(v, 0.f);
                    o4[r] = (_Float16)v;
                }
                *(f16x4*)((_Float16*)out + pvox * 8 + quad * 4) = o4;
            }
        } else { // OM == 2, OC = 1, padded planar out
            if (quad == 0) {
                const size_t pvox = (size_t)(d + 1) * PHW + (size_t)(h + 1) * PW + 1 + wv;
                float v = acc[0];
                if (RELU) v = fmaxf(v, 0.f);
                stv((TO*)out + pvox, v);
            }
        }
    }
}

// ==========================================================================
// conv27_g: the 8->27 weight conv via MFMA 32x32x16 f16 + L1-normalize.
// One 32x32 tile holds all 27 OC rows -> 14 MFMAs per 32 voxels (K=224,
// tap 27 zero-padded in A). Lane: col=lane&31 (voxel), half=lane>>5.
// Epilogue: norm = 15 in-lane |.| adds + 1 shfl_xor(32) + v_rcp; store the
// 16 C-regs DIRECTLY (C-layout order) as 32 contiguous bytes at
// wn[vox*32 + half*16] — no transpose, no bpermute. adapt* index via WPOS.
// ==========================================================================
__global__ __launch_bounds__(256) void conv27_g(const _Float16* __restrict__ in,
                                                const _Float16* __restrict__ apack,
                                                _Float16* __restrict__ wn)
{
    const int tid  = threadIdx.x;
    const int wid  = tid >> 6;
    const int lane = tid & 63;
    const int col  = lane & 31;
    const int half = lane >> 5;

    const int bid = blockIdx.x;            // 4096 blocks x 4 waves = 16384 (d,h) rows
    const int idx = bid >> 3;
    const int d   = ((bid & 7) << 4) + (idx & 15);
    const int h   = ((idx >> 4) << 2) + wid;

    f16x8 afr[14];
#pragma unroll
    for (int s = 0; s < 14; ++s)
        afr[s] = *(const f16x8*)(apack + (size_t)(s * 64 + lane) * 8);

    // B geometry: MFMA s consumes taps (2s, 2s+1); this lane supplies tap 2s+half.
    int voff[14];
#pragma unroll
    for (int s = 0; s < 14; ++s) {
        int tap = 2 * s + half;
        if (tap > 26) tap = 26;            // A row zero there
        const int kd = tap / 9, kh = (tap % 9) / 3, kw = tap % 3;
        voff[s] = (d + kd) * PHW + (h + kh) * PW + kw;
    }

#pragma unroll 1
    for (int wseg = 0; wseg < 4; ++wseg) {
        const int wv = wseg * 32 + col;
        f16x8 bfr[14];
#pragma unroll
        for (int s = 0; s < 14; ++s)
            bfr[s] = *(const f16x8*)(in + (size_t)(voff[s] + wv) * 8);
        f32x16 acc = {};
#pragma unroll
        for (int s = 0; s < 14; ++s)
            acc = __builtin_amdgcn_mfma_f32_32x32x16_f16(afr[s], bfr[s], acc, 0, 0, 0);

        // ---- L1 norm over the 27 rows (rows 27-31 are exact zeros) ----
        float p0 = (fabsf(acc[0]) + fabsf(acc[1])) + (fabsf(acc[2]) + fabsf(acc[3]));
        float p1 = (fabsf(acc[4]) + fabsf(acc[5])) + (fabsf(acc[6]) + fabsf(acc[7]));
        float p2 = (fabsf(acc[8]) + fabsf(acc[9])) + (fabsf(acc[10]) + fabsf(acc[11]));
        float p3 = (fabsf(acc[12]) + fabsf(acc[13])) + (fabsf(acc[14]) + fabsf(acc[15]));
        float ssum = (p0 + p1) + (p2 + p3);
        ssum += __shfl_xor(ssum, 32);
        const float inv = __builtin_amdgcn_rcpf(fmaxf(ssum, 1e-12f));

        // ---- scale, pack, store 32B contiguous (C-layout order) ----
        int pk[8];
#pragma unroll
        for (int i = 0; i < 8; ++i) {
            f16x2 t;
            t[0] = (_Float16)(acc[2 * i] * inv);
            t[1] = (_Float16)(acc[2 * i + 1] * inv);
            pk[i] = __builtin_bit_cast(int, t);
        }
        const size_t vox = (size_t)d * HW + (size_t)h * WW + wv;   // unpadded
        _Float16* dst = wn + (vox << 5) + (half << 4);
        int4v v0; v0[0] = pk[0]; v0[1] = pk[1]; v0[2] = pk[2]; v0[3] = pk[3];
        int4v v1; v1[0] = pk[4]; v1[1] = pk[5]; v1[2] = pk[6]; v1[3] = pk[7];
        *(int4v*)dst = v0;
        *(int4v*)(dst + 8) = v1;
    }
}

// ==========================================================================
// adapt8: per-voxel 27-tap weights (unpadded [vox][32] fp16, C-layout order
// via WPOS), 8 interleaved channels, PADDED in/out — no bounds checks.
// ==========================================================================
__global__ __launch_bounds__(256) void adapt8(const _Float16* __restrict__ in,
                                              const _Float16* __restrict__ wn,
                                              _Float16* __restrict__ out)
{
    const int tid = threadIdx.x;
    const int bid = blockIdx.x;            // 8192 = 128 d x 64 h-pairs
    const int d = bid >> 6;
    const int h = ((bid & 63) << 1) + (tid >> 7);
    const int w = tid & 127;
    const size_t vox = (size_t)d * HW + (size_t)h * WW + w;   // unpadded (weights)

    const f16x8* wrow = (const f16x8*)(wn + (vox << 5));
    f16x8 wkv[4];
#pragma unroll
    for (int j = 0; j < 4; ++j) wkv[j] = wrow[j];

    float acc[8] = {0.f, 0.f, 0.f, 0.f, 0.f, 0.f, 0.f, 0.f};
#pragma unroll
    for (int kd = 0; kd < 3; ++kd) {
#pragma unroll
        for (int kh = 0; kh < 3; ++kh) {
            const _Float16* rp = in + ((size_t)(d + kd) * PHW + (size_t)(h + kh) * PW + w) * 8;
#pragma unroll
            for (int kw = 0; kw < 3; ++kw) {
                const f16x8 xv = *(const f16x8*)(rp + (size_t)kw * 8);
                const int t = WPOS(kd * 9 + kh * 3 + kw);
                const float wvv = (float)wkv[t >> 3][t & 7];
#pragma unroll
                for (int c = 0; c < 8; ++c) acc[c] += wvv * (float)xv[c];
            }
        }
    }
    f16x8 o;
#pragma unroll
    for (int c = 0; c < 8; ++c) o[c] = (_Float16)acc[c];
    *(f16x8*)(out + ((size_t)(d + 1) * PHW + (size_t)(h + 1) * PW + (w + 1)) * 8) = o;
}

// ==========================================================================
// adapt1: 1 channel, PADDED planar f16 in; weights unpadded [vox][32]
// (C-layout order via WPOS). PADOUT: padded f16 out, else unpadded out.
// ==========================================================================
template <bool PADOUT, typename TOUT>
__global__ __launch_bounds__(256) void adapt1(const _Float16* __restrict__ in,
                                              const _Float16* __restrict__ wn,
                                              TOUT* __restrict__ out)
{
    const size_t vox = (size_t)blockIdx.x * 256 + threadIdx.x;
    const int w = (int)(vox & 127);
    const int h = (int)((vox >> 7) & 127);
    const int d = (int)(vox >> 14);

    const f16x8* wrow = (const f16x8*)(wn + (vox << 5));
    f16x8 wkv[4];
#pragma unroll
    for (int j = 0; j < 4; ++j) wkv[j] = wrow[j];

    float acc = 0.f;
#pragma unroll
    for (int kd = 0; kd < 3; ++kd) {
#pragma unroll
        for (int kh = 0; kh < 3; ++kh) {
            const _Float16* rp = in + (size_t)(d + kd) * PHW + (size_t)(h + kh) * PW + w;
#pragma unroll
            for (int kw = 0; kw < 3; ++kw) {
                const int t = WPOS(kd * 9 + kh * 3 + kw);
                acc += (float)wkv[t >> 3][t & 7] * (float)rp[kw];
            }
        }
    }
    if (PADOUT)
        stv(out + (size_t)(d + 1) * PHW + (size_t)(h + 1) * PW + (w + 1), acc);
    else
        stv(out + vox, acc);
}

extern "C" void kernel_launch(void* const* d_in, const int* in_sizes, int n_in,
                              void* d_out, int out_size, void* d_ws, size_t ws_size,
                              hipStream_t stream)
{
    (void)in_sizes; (void)n_in; (void)out_size; (void)ws_size;

    const float* x      = (const float*)d_in[0];
    const float* ac1_w1 = (const float*)d_in[1];
    const float* ac1_b1 = (const float*)d_in[2];
    const float* ac1_w2 = (const float*)d_in[3];
    const float* ac2_w1 = (const float*)d_in[4];
    const float* ac2_b1 = (const float*)d_in[5];
    const float* ac2_w2 = (const float*)d_in[6];
    const float* ac3_w1 = (const float*)d_in[7];
    const float* ac3_b1 = (const float*)d_in[8];
    const float* ac3_w2 = (const float*)d_in[9];
    const float* mid_w  = (const float*)d_in[10];
    const float* mid_b  = (const float*)d_in[11];
    const float* out_w  = (const float*)d_in[12];
    const float* out_b  = (const float*)d_in[13];
    float* outp = (float*)d_out;

    // fp16 scratch (213 MB, ws >= 236 MB per R2 forensics):
    // Wb [vox][32] (32V) | B1i 8*PVOL padded | B2i 8*PVOL padded
    // | F0 PVOL padded planar | F1 PVOL | packs
    const size_t V = (size_t)VOL;
    _Float16* Wb  = (_Float16*)d_ws;
    _Float16* B1i = Wb + 32 * V;
    _Float16* B2i = B1i + (size_t)8 * PVOL;
    _Float16* F0  = B2i + (size_t)8 * PVOL;
    _Float16* F1  = F0 + (size_t)PVOL;
    _Float16* PB  = F1 + (size_t)PVOL;

    _Float16* pk_ac1w1 = PB + 0;
    _Float16* pk_ac2w1 = PB + 3584;
    _Float16* pk_ac3w1 = PB + 7168;
    _Float16* pk_midw  = PB + 10752;
    _Float16* pk_outw  = PB + 14336;
    _Float16* pk_ac1w2 = PB + 17920;
    _Float16* pk_ac2w2 = PB + 25088;
    _Float16* pk_ac3w2 = PB + 32256;

    const dim3 cgrid(4096), cblk(256);
    const dim3 a8grid(8192), a8blk(256);
    const dim3 a1grid(8192), a1blk(256);
    const dim3 zgrid((NSHELL + 255) / 256), zblk(256);

    // zero only the pad shells (~3.6 MB total vs 79 MB full-buffer zero)
    zero_shell<8><<<zgrid, zblk, 0, stream>>>(B1i);
    zero_shell<8><<<zgrid, zblk, 0, stream>>>(B2i);
    zero_shell<1><<<zgrid, zblk, 0, stream>>>(F0);
    zero_shell<1><<<zgrid, zblk, 0, stream>>>(F1);
    prepack_all<<<8, 256, 0, stream>>>(ac1_w1, ac2_w1, ac3_w1, mid_w, out_w,
                                       ac1_w2, ac2_w2, ac3_w2, PB);
    cvt_x<<<8192, 256, 0, stream>>>(x, B2i);                                   // B2i = x

    // ---- adaptive block 1 (input x = B2i) ----
    conv_g<8, true, 0, _Float16><<<cgrid, cblk, 0, stream>>>(B2i, pk_ac1w1, ac1_b1, B1i);
    conv27_g<<<cgrid, cblk, 0, stream>>>(B1i, pk_ac1w2, Wb);
    adapt8<<<a8grid, a8blk, 0, stream>>>(B2i, Wb, B1i);
    adapt8<<<a8grid, a8blk, 0, stream>>>(B1i, Wb, B2i);
    adapt8<<<a8grid, a8blk, 0, stream>>>(B2i, Wb, B1i);                        // B1i = block1 out
    conv_g<8, false, 0, _Float16><<<cgrid, cblk, 0, stream>>>(B1i, pk_midw, mid_b, B2i); // B2i = mid

    // ---- adaptive block 2 (input mid = B2i) ----
    conv_g<8, true, 0, _Float16><<<cgrid, cblk, 0, stream>>>(B2i, pk_ac2w1, ac2_b1, B1i);
    conv27_g<<<cgrid, cblk, 0, stream>>>(B1i, pk_ac2w2, Wb);
    adapt8<<<a8grid, a8blk, 0, stream>>>(B2i, Wb, B1i);
    adapt8<<<a8grid, a8blk, 0, stream>>>(B1i, Wb, B2i);
    adapt8<<<a8grid, a8blk, 0, stream>>>(B2i, Wb, B1i);                        // B1i = mid2

    // ---- block 3: weights from mid2 = B1i ----
    conv_g<8, true, 0, _Float16><<<cgrid, cblk, 0, stream>>>(B1i, pk_ac3w1, ac3_b1, B2i);
    conv27_g<<<cgrid, cblk, 0, stream>>>(B2i, pk_ac3w2, Wb);
    conv_g<1, false, 2, _Float16><<<cgrid, cblk, 0, stream>>>(B1i, pk_outw, out_b, F0);
    adapt1<true, _Float16><<<a1grid, a1blk, 0, stream>>>(F0, Wb, F1);
    adapt1<true, _Float16><<<a1grid, a1blk, 0, stream>>>(F1, Wb, F0);
    adapt1<false, float><<<a1grid, a1blk, 0, stream>>>(F0, Wb, outp);
}